// Round 1
// baseline (358.306 us; speedup 1.0000x reference)
//
#include <hip/hip_runtime.h>
#include <hip/hip_bf16.h>

#define NE   8
#define NTOK 8192
#define DH   768
#define DI   3072
#define CAP  1024   // tokens per expert

typedef __bf16 bf16x8 __attribute__((ext_vector_type(8)));
typedef float  f32x4  __attribute__((ext_vector_type(4)));

__device__ __forceinline__ void gload_lds16(const void* g, void* l) {
  __builtin_amdgcn_global_load_lds(
      (const __attribute__((address_space(1))) unsigned int*)g,
      (__attribute__((address_space(3))) unsigned int*)l, 16, 0, 0);
}

// ---------------- prep: transpose + f32->bf16 ([R][C] -> [C][R]) ----------------
__global__ __launch_bounds__(256)
void transpose_cvt(const float* __restrict__ in, __hip_bfloat16* __restrict__ out,
                   int R, int C) {
  __shared__ float tile[32][33];
  const int e = blockIdx.z;
  const float* src = in + (size_t)e * R * C;
  __hip_bfloat16* dst = out + (size_t)e * R * C;
  const int c0 = blockIdx.x * 32, r0 = blockIdx.y * 32;
  const int tx = threadIdx.x, ty = threadIdx.y;  // 32 x 8
#pragma unroll
  for (int j = 0; j < 4; ++j)
    tile[ty + 8 * j][tx] = src[(size_t)(r0 + ty + 8 * j) * C + c0 + tx];
  __syncthreads();
#pragma unroll
  for (int j = 0; j < 4; ++j)
    dst[(size_t)(c0 + ty + 8 * j) * R + r0 + tx] = __float2bfloat16(tile[tx][ty + 8 * j]);
}

// ---------------- prep: gather tokens by expert + f32->bf16 ----------------
// xs[e][c][k] = bf16(x[c*8+e][k]); one thread handles 8 contiguous k.
__global__ __launch_bounds__(256)
void gather_cvt_x(const float* __restrict__ x, __hip_bfloat16* __restrict__ xs) {
  const int j = blockIdx.x * 256 + threadIdx.x;   // 0 .. 8192*96
  const int orow = j / 96;
  const int k8 = (j - orow * 96) * 8;
  const int e = orow >> 10, c = orow & 1023;
  const int tok = c * 8 + e;
  const float4* p = (const float4*)(x + (size_t)tok * DH + k8);
  float4 u = p[0], v = p[1];
  __hip_bfloat16 tmp[8];
  tmp[0] = __float2bfloat16(u.x); tmp[1] = __float2bfloat16(u.y);
  tmp[2] = __float2bfloat16(u.z); tmp[3] = __float2bfloat16(u.w);
  tmp[4] = __float2bfloat16(v.x); tmp[5] = __float2bfloat16(v.y);
  tmp[6] = __float2bfloat16(v.z); tmp[7] = __float2bfloat16(v.w);
  *(uint4*)(xs + (size_t)orow * DH + k8) = *(const uint4*)tmp;
}

// ---------------- grouped GEMM, m97 structure ----------------
// C[m][n] = sum_k A[m][k]*Bt[n][k]  (A row-major [M][K], Bt row-major [N][K])
// 128x128 tile, BK=64, 4 waves (2x2 of 64x64), 16x16x32 bf16 MFMA,
// global_load_lds staging with pre-swizzled source (XOR-16B-column swizzle).
// EPI==0: out bf16 = gelu(acc + bias);  EPI==1: out f32 = acc + bias.
template <int EPI>
__global__ __launch_bounds__(256)
void gemm_bt(const __hip_bfloat16* __restrict__ A,
             const __hip_bfloat16* __restrict__ Bt,
             const float* __restrict__ bias,
             void* __restrict__ OutP,
             int N, int K, int NK,
             size_t sAe, size_t sBe, size_t sOe, int sBias) {
  __shared__ __hip_bfloat16 As[128 * 64];
  __shared__ __hip_bfloat16 Bs[128 * 64];

  const int t = threadIdx.x;
  const int lane = t & 63;
  const int w = t >> 6;
  const int g = lane >> 4;
  const int l15 = lane & 15;
  const int wm = w >> 1, wn = w & 1;
  const int e = blockIdx.z;

  const __hip_bfloat16* Ae = A + (size_t)e * sAe + (size_t)blockIdx.y * 128 * K;
  const __hip_bfloat16* Be = Bt + (size_t)e * sBe + (size_t)blockIdx.x * 128 * K;

  // staging map: LDS linear slot (i*256+t)*16B == row (i*32 + t/8), 16B-col (t%8).
  // swizzled content: element k-offset = ((t%8) ^ (row&7))*8, row&7 == (t>>3)&7.
  const int rowStg = t >> 3;
  const int srcOff = ((t & 7) ^ (rowStg & 7)) * 8;
  const size_t stgBase = (size_t)rowStg * K + srcOff;

  f32x4 acc[4][4] = {};

  for (int kt = 0; kt < NK; ++kt) {
    const int k0 = kt * 64;
#pragma unroll
    for (int i = 0; i < 4; ++i) {
      gload_lds16(Ae + stgBase + (size_t)i * 32 * K + k0, (char*)As + (i * 256 + t) * 16);
      gload_lds16(Be + stgBase + (size_t)i * 32 * K + k0, (char*)Bs + (i * 256 + t) * 16);
    }
    __syncthreads();
#pragma unroll
    for (int ks = 0; ks < 2; ++ks) {
      bf16x8 af[4], bv[4];
#pragma unroll
      for (int fm = 0; fm < 4; ++fm) {
        const int r = wm * 64 + fm * 16 + l15;
        af[fm] = *(const bf16x8*)((const char*)As + r * 128 + ((ks * 4 + g) ^ (r & 7)) * 16);
      }
#pragma unroll
      for (int fn = 0; fn < 4; ++fn) {
        const int r = wn * 64 + fn * 16 + l15;
        bv[fn] = *(const bf16x8*)((const char*)Bs + r * 128 + ((ks * 4 + g) ^ (r & 7)) * 16);
      }
#pragma unroll
      for (int fm = 0; fm < 4; ++fm)
#pragma unroll
        for (int fn = 0; fn < 4; ++fn)
          acc[fm][fn] = __builtin_amdgcn_mfma_f32_16x16x32_bf16(af[fm], bv[fn], acc[fm][fn], 0, 0, 0);
    }
    __syncthreads();
  }

  const float* biasE = bias + (size_t)e * sBias + blockIdx.x * 128;
  if (EPI == 0) {
    __hip_bfloat16* O = (__hip_bfloat16*)OutP + (size_t)e * sOe +
                        (size_t)blockIdx.y * 128 * N + blockIdx.x * 128;
#pragma unroll
    for (int fm = 0; fm < 4; ++fm)
#pragma unroll
      for (int fn = 0; fn < 4; ++fn) {
        const int n = wn * 64 + fn * 16 + l15;
        const float bvv = biasE[n];
#pragma unroll
        for (int r = 0; r < 4; ++r) {
          const int m = wm * 64 + fm * 16 + g * 4 + r;
          float v = acc[fm][fn][r] + bvv;
          v = 0.5f * v * (1.0f + erff(v * 0.70710678118654752f));  // exact gelu
          O[(size_t)m * N + n] = __float2bfloat16(v);
        }
      }
  } else {
    float* O = (float*)OutP + (size_t)e * sOe +
               (size_t)blockIdx.y * 128 * N + blockIdx.x * 128;
#pragma unroll
    for (int fm = 0; fm < 4; ++fm)
#pragma unroll
      for (int fn = 0; fn < 4; ++fn) {
        const int n = wn * 64 + fn * 16 + l15;
        const float bvv = biasE[n];
#pragma unroll
        for (int r = 0; r < 4; ++r) {
          const int m = wm * 64 + fm * 16 + g * 4 + r;
          O[(size_t)m * N + n] = acc[fm][fn][r] + bvv;
        }
      }
  }
}

// ---------------- residual + LayerNorm + scatter ----------------
__global__ __launch_bounds__(256)
void resid_ln(const float* __restrict__ y, const float* __restrict__ x,
              const float* __restrict__ gamma, const float* __restrict__ beta,
              float* __restrict__ out) {
  const int row = blockIdx.x;            // e*1024 + c
  const int e = row >> 10, c = row & 1023;
  const int tok = c * 8 + e;
  const float* yr = y + (size_t)row * DH;
  const float* xr = x + (size_t)tok * DH;
  const int t = threadIdx.x;
  float z[3];
  float s = 0.f, s2 = 0.f;
#pragma unroll
  for (int j = 0; j < 3; ++j) {
    const float v = yr[t + 256 * j] + xr[t + 256 * j];
    z[j] = v; s += v; s2 += v * v;
  }
#pragma unroll
  for (int off = 32; off; off >>= 1) {
    s += __shfl_down(s, off);
    s2 += __shfl_down(s2, off);
  }
  __shared__ float rs[4], rs2[4];
  if ((t & 63) == 0) { rs[t >> 6] = s; rs2[t >> 6] = s2; }
  __syncthreads();
  const float S = rs[0] + rs[1] + rs[2] + rs[3];
  const float S2 = rs2[0] + rs2[1] + rs2[2] + rs2[3];
  const float mu = S * (1.0f / DH);
  const float var = S2 * (1.0f / DH) - mu * mu;
  const float rstd = rsqrtf(var + 1e-12f);
  const float* ga = gamma + (size_t)e * DH;
  const float* be = beta + (size_t)e * DH;
  float* orow = out + (size_t)tok * DH;
#pragma unroll
  for (int j = 0; j < 3; ++j) {
    const int h = t + 256 * j;
    orow[h] = (z[j] - mu) * rstd * ga[h] + be[h];
  }
}

extern "C" void kernel_launch(void* const* d_in, const int* in_sizes, int n_in,
                              void* d_out, int out_size, void* d_ws, size_t ws_size,
                              hipStream_t stream) {
  const float* x     = (const float*)d_in[0];
  // d_in[1] task_ids: protocol is expert = token % 8 (arange ids) -> fixed permutation
  const float* W1    = (const float*)d_in[2];
  const float* b1    = (const float*)d_in[3];
  const float* W2    = (const float*)d_in[4];
  const float* b2    = (const float*)d_in[5];
  const float* gamma = (const float*)d_in[6];
  const float* beta  = (const float*)d_in[7];
  float* out = (float*)d_out;

  // ws layout (elements): W1t bf16 [E][DI][DH] | W2t bf16 [E][DH][DI] |
  //                       h bf16 [E][CAP][DI]  | region C: xs bf16 [E][CAP][DH] reused as y f32
  __hip_bfloat16* W1t = (__hip_bfloat16*)d_ws;
  __hip_bfloat16* W2t = W1t + (size_t)NE * DH * DI;
  __hip_bfloat16* hbuf = W2t + (size_t)NE * DH * DI;
  __hip_bfloat16* xs = hbuf + (size_t)NTOK * DI;
  float* ybuf = (float*)xs;   // xs dead after GEMM1; y written by GEMM2

  dim3 tb(32, 8);
  // W1 [E][768][3072] -> W1t [E][3072][768]
  transpose_cvt<<<dim3(DI / 32, DH / 32, NE), tb, 0, stream>>>(W1, W1t, DH, DI);
  // W2 [E][3072][768] -> W2t [E][768][3072]
  transpose_cvt<<<dim3(DH / 32, DI / 32, NE), tb, 0, stream>>>(W2, W2t, DI, DH);
  gather_cvt_x<<<(NTOK * (DH / 8)) / 256, 256, 0, stream>>>(x, xs);

  // GEMM1: h = gelu(xs @ W1 + b1)   M=1024 N=3072 K=768
  gemm_bt<0><<<dim3(DI / 128, CAP / 128, NE), 256, 0, stream>>>(
      xs, W1t, b1, hbuf, DI, DH, DH / 64,
      (size_t)CAP * DH, (size_t)DI * DH, (size_t)CAP * DI, DI);

  // GEMM2: y = h @ W2 + b2          M=1024 N=768 K=3072
  gemm_bt<1><<<dim3(DH / 128, CAP / 128, NE), 256, 0, stream>>>(
      hbuf, W2t, b2, ybuf, DH, DI, DI / 64,
      (size_t)CAP * DI, (size_t)DH * DI, (size_t)CAP * DH, DH);

  resid_ln<<<NTOK, 256, 0, stream>>>(ybuf, x, gamma, beta, out);
}

// Round 2
// 349.699 us; speedup vs baseline: 1.0246x; 1.0246x over previous
//
#include <hip/hip_runtime.h>
#include <hip/hip_bf16.h>

#define NE   8
#define NTOK 8192
#define DH   768
#define DI   3072
#define CAP  1024   // tokens per expert

typedef __bf16 bf16x8 __attribute__((ext_vector_type(8)));
typedef float  f32x4  __attribute__((ext_vector_type(4)));

__device__ __forceinline__ void gload_lds16(const void* g, void* l) {
  __builtin_amdgcn_global_load_lds(
      (const __attribute__((address_space(1))) unsigned int*)g,
      (__attribute__((address_space(3))) unsigned int*)l, 16, 0, 0);
}

// ---------------- prep: transpose + f32->bf16 ([R][C] -> [C][R]) ----------------
// 64x64 tile. float4 global reads, XOR-swizzled f32 LDS (2-way max on readout),
// uint4 (8x bf16) global writes in 128B-contiguous groups of 8 lanes.
__global__ __launch_bounds__(256)
void transpose_cvt(const float* __restrict__ in, __hip_bfloat16* __restrict__ out,
                   int R, int C) {
  __shared__ float lds[64 * 64];
  const int e = blockIdx.z;
  const float* src = in + (size_t)e * R * C;
  __hip_bfloat16* dst = out + (size_t)e * R * C;
  const int c0 = blockIdx.x * 64, r0 = blockIdx.y * 64;
  const int t = threadIdx.x;

  // store phase: element (r,c) -> lds[r*64 + ((c>>2) ^ ((r>>3)&7))*4 + (c&3)]
  {
    const int rr = t >> 4;         // 0..15
    const int cq = t & 15;         // quad index 0..15
#pragma unroll
    for (int j = 0; j < 4; ++j) {
      const int r = rr + 16 * j;
      const float4 v = *(const float4*)(src + (size_t)(r0 + r) * C + c0 + cq * 4);
      *(float4*)&lds[r * 64 + ((cq ^ ((r >> 3) & 7)) << 2)] = v;
    }
  }
  __syncthreads();
  // readout phase: thread t -> rows r8..r8+7 of output column c
  {
    const int r8 = (t & 7) * 8;
    const int cb = t >> 3;         // 0..31
#pragma unroll
    for (int j = 0; j < 2; ++j) {
      const int c = cb + 32 * j;
      __hip_bfloat16 tmp[8];
#pragma unroll
      for (int i = 0; i < 8; ++i) {
        const int rr = r8 + i;
        tmp[i] = __float2bfloat16(
            lds[rr * 64 + ((((c >> 2) ^ ((rr >> 3) & 7)) << 2) | (c & 3))]);
      }
      *(uint4*)(dst + (size_t)(c0 + c) * R + r0 + r8) = *(const uint4*)tmp;
    }
  }
}

// ---------------- prep: gather tokens by expert + f32->bf16 ----------------
__global__ __launch_bounds__(256)
void gather_cvt_x(const float* __restrict__ x, __hip_bfloat16* __restrict__ xs) {
  const int j = blockIdx.x * 256 + threadIdx.x;   // 0 .. 8192*96
  const int orow = j / 96;
  const int k8 = (j - orow * 96) * 8;
  const int e = orow >> 10, c = orow & 1023;
  const int tok = c * 8 + e;
  const float4* p = (const float4*)(x + (size_t)tok * DH + k8);
  float4 u = p[0], v = p[1];
  __hip_bfloat16 tmp[8];
  tmp[0] = __float2bfloat16(u.x); tmp[1] = __float2bfloat16(u.y);
  tmp[2] = __float2bfloat16(u.z); tmp[3] = __float2bfloat16(u.w);
  tmp[4] = __float2bfloat16(v.x); tmp[5] = __float2bfloat16(v.y);
  tmp[6] = __float2bfloat16(v.z); tmp[7] = __float2bfloat16(v.w);
  *(uint4*)(xs + (size_t)orow * DH + k8) = *(const uint4*)tmp;
}

// ---------------- grouped GEMM, m97 structure + XCD swizzle + split-K ----------
// out[m][n] = sum_k A[m][k]*Bt[n][k].  1D grid; decode:
//   chunk-per-XCD swizzle (nblk % 8 == 0), then id -> (e, s, bx, by), by fastest.
// EPI==0: bf16 out = gelu(acc+bias).  EPI==1: f32 out = acc + (s==0 ? bias : 0),
//   written to OutP + s*sSplit (split-K partials).
template <int EPI>
__global__ __launch_bounds__(256)
void gemm_bt(const __hip_bfloat16* __restrict__ A,
             const __hip_bfloat16* __restrict__ Bt,
             const float* __restrict__ bias,
             void* __restrict__ OutP,
             int N, int K, int KK, int gx, int gy, int nsplit,
             size_t sAe, size_t sBe, size_t sOe, int sBias, size_t sSplit) {
  __shared__ __hip_bfloat16 As[128 * 64];
  __shared__ __hip_bfloat16 Bs[128 * 64];

  // ---- block-id decode with XCD swizzle ----
  const int nblk = gridDim.x;
  const int chunk = nblk >> 3;
  const int id = (blockIdx.x & 7) * chunk + (blockIdx.x >> 3);
  const int per_e = gx * gy * nsplit;
  const int e = id / per_e;
  int r = id - e * per_e;
  const int s = r / (gx * gy);
  r -= s * (gx * gy);
  const int bx = r / gy;
  const int by = r - bx * gy;

  const int t = threadIdx.x;
  const int lane = t & 63;
  const int w = t >> 6;
  const int g = lane >> 4;
  const int l15 = lane & 15;
  const int wm = w >> 1, wn = w & 1;

  const __hip_bfloat16* Ae = A + (size_t)e * sAe + (size_t)by * 128 * K;
  const __hip_bfloat16* Be = Bt + (size_t)e * sBe + (size_t)bx * 128 * K;

  const int rowStg = t >> 3;
  const int srcOff = ((t & 7) ^ (rowStg & 7)) * 8;
  const size_t stgBase = (size_t)rowStg * K + srcOff;

  f32x4 acc[4][4] = {};

  for (int kt = 0; kt < KK; ++kt) {
    const int k0 = (s * KK + kt) * 64;
#pragma unroll
    for (int i = 0; i < 4; ++i) {
      gload_lds16(Ae + stgBase + (size_t)i * 32 * K + k0, (char*)As + (i * 256 + t) * 16);
      gload_lds16(Be + stgBase + (size_t)i * 32 * K + k0, (char*)Bs + (i * 256 + t) * 16);
    }
    __syncthreads();
#pragma unroll
    for (int ks = 0; ks < 2; ++ks) {
      bf16x8 af[4], bv[4];
#pragma unroll
      for (int fm = 0; fm < 4; ++fm) {
        const int rA = wm * 64 + fm * 16 + l15;
        af[fm] = *(const bf16x8*)((const char*)As + rA * 128 + ((ks * 4 + g) ^ (rA & 7)) * 16);
      }
#pragma unroll
      for (int fn = 0; fn < 4; ++fn) {
        const int rB = wn * 64 + fn * 16 + l15;
        bv[fn] = *(const bf16x8*)((const char*)Bs + rB * 128 + ((ks * 4 + g) ^ (rB & 7)) * 16);
      }
#pragma unroll
      for (int fm = 0; fm < 4; ++fm)
#pragma unroll
        for (int fn = 0; fn < 4; ++fn)
          acc[fm][fn] = __builtin_amdgcn_mfma_f32_16x16x32_bf16(af[fm], bv[fn], acc[fm][fn], 0, 0, 0);
    }
    __syncthreads();
  }

  const float* biasE = bias + (size_t)e * sBias + bx * 128;
  if (EPI == 0) {
    __hip_bfloat16* O = (__hip_bfloat16*)OutP + (size_t)e * sOe +
                        (size_t)by * 128 * N + bx * 128;
#pragma unroll
    for (int fm = 0; fm < 4; ++fm)
#pragma unroll
      for (int fn = 0; fn < 4; ++fn) {
        const int n = wn * 64 + fn * 16 + l15;
        const float bvv = biasE[n];
#pragma unroll
        for (int rg = 0; rg < 4; ++rg) {
          const int m = wm * 64 + fm * 16 + g * 4 + rg;
          float v = acc[fm][fn][rg] + bvv;
          v = 0.5f * v * (1.0f + erff(v * 0.70710678118654752f));  // exact gelu
          O[(size_t)m * N + n] = __float2bfloat16(v);
        }
      }
  } else {
    float* O = (float*)OutP + (size_t)s * sSplit + (size_t)e * sOe +
               (size_t)by * 128 * N + bx * 128;
#pragma unroll
    for (int fm = 0; fm < 4; ++fm)
#pragma unroll
      for (int fn = 0; fn < 4; ++fn) {
        const int n = wn * 64 + fn * 16 + l15;
        const float bvv = (s == 0) ? biasE[n] : 0.0f;
#pragma unroll
        for (int rg = 0; rg < 4; ++rg) {
          const int m = wm * 64 + fm * 16 + g * 4 + rg;
          O[(size_t)m * N + n] = acc[fm][fn][rg] + bvv;
        }
      }
  }
}

// ---------------- residual + (split-sum) + LayerNorm + scatter ----------------
__global__ __launch_bounds__(256)
void resid_ln(const float* __restrict__ y0, const float* __restrict__ y1, int two,
              const float* __restrict__ x,
              const float* __restrict__ gamma, const float* __restrict__ beta,
              float* __restrict__ out) {
  const int row = blockIdx.x;            // e*1024 + c
  const int e = row >> 10, c = row & 1023;
  const int tok = c * 8 + e;
  const float* y0r = y0 + (size_t)row * DH;
  const float* y1r = y1 + (size_t)row * DH;
  const float* xr = x + (size_t)tok * DH;
  const int t = threadIdx.x;
  float z[3];
  float s = 0.f, s2 = 0.f;
#pragma unroll
  for (int j = 0; j < 3; ++j) {
    float v = y0r[t + 256 * j] + xr[t + 256 * j];
    if (two) v += y1r[t + 256 * j];
    z[j] = v; s += v; s2 += v * v;
  }
#pragma unroll
  for (int off = 32; off; off >>= 1) {
    s += __shfl_down(s, off);
    s2 += __shfl_down(s2, off);
  }
  __shared__ float rs[4], rs2[4];
  if ((t & 63) == 0) { rs[t >> 6] = s; rs2[t >> 6] = s2; }
  __syncthreads();
  const float S = rs[0] + rs[1] + rs[2] + rs[3];
  const float S2 = rs2[0] + rs2[1] + rs2[2] + rs2[3];
  const float mu = S * (1.0f / DH);
  const float var = S2 * (1.0f / DH) - mu * mu;
  const float rstd = rsqrtf(var + 1e-12f);
  const float* ga = gamma + (size_t)e * DH;
  const float* be = beta + (size_t)e * DH;
  float* orow = out + (size_t)tok * DH;
#pragma unroll
  for (int j = 0; j < 3; ++j) {
    const int h = t + 256 * j;
    orow[h] = (z[j] - mu) * rstd * ga[h] + be[h];
  }
}

extern "C" void kernel_launch(void* const* d_in, const int* in_sizes, int n_in,
                              void* d_out, int out_size, void* d_ws, size_t ws_size,
                              hipStream_t stream) {
  const float* x     = (const float*)d_in[0];
  // d_in[1] task_ids: protocol is expert = token % 8 (arange ids) -> fixed perm
  const float* W1    = (const float*)d_in[2];
  const float* b1    = (const float*)d_in[3];
  const float* W2    = (const float*)d_in[4];
  const float* b2    = (const float*)d_in[5];
  const float* gamma = (const float*)d_in[6];
  const float* beta  = (const float*)d_in[7];
  float* out = (float*)d_out;

  // ws layout (bytes):
  //   0          W1t bf16 [E][DI][DH]   (37,748,736)
  //   37748736   W2t bf16 [E][DH][DI]   (37,748,736)
  //   75497472   h   bf16 [E][CAP][DI]  (50,331,648)
  //   125829120  xs  bf16 [E][CAP][DH]  (12.6M), reused as y0 f32 (25,165,824)
  //   150994944  y1  f32  [E][CAP][DH]  (25,165,824)  -- only if ws permits
  char* base = (char*)d_ws;
  __hip_bfloat16* W1t  = (__hip_bfloat16*)base;
  __hip_bfloat16* W2t  = (__hip_bfloat16*)(base + 37748736ull);
  __hip_bfloat16* hbuf = (__hip_bfloat16*)(base + 75497472ull);
  __hip_bfloat16* xs   = (__hip_bfloat16*)(base + 125829120ull);
  float* y0 = (float*)xs;                      // xs dead after GEMM1
  float* y1 = (float*)(base + 150994944ull);
  const int nsplit = (ws_size >= 176160768ull) ? 2 : 1;

  // W1 [E][768][3072] -> W1t [E][3072][768]
  transpose_cvt<<<dim3(DI / 64, DH / 64, NE), 256, 0, stream>>>(W1, W1t, DH, DI);
  // W2 [E][3072][768] -> W2t [E][768][3072]
  transpose_cvt<<<dim3(DH / 64, DI / 64, NE), 256, 0, stream>>>(W2, W2t, DI, DH);
  gather_cvt_x<<<(NTOK * (DH / 8)) / 256, 256, 0, stream>>>(x, xs);

  // GEMM1: h = gelu(xs @ W1 + b1)   per-expert M=1024 N=3072 K=768
  gemm_bt<0><<<(DI / 128) * (CAP / 128) * NE, 256, 0, stream>>>(
      xs, W1t, b1, hbuf, DI, DH, DH / 64, DI / 128, CAP / 128, 1,
      (size_t)CAP * DH, (size_t)DI * DH, (size_t)CAP * DI, DI, 0);

  // GEMM2: y = h @ W2 + b2          per-expert M=1024 N=768 K=3072, split-K
  gemm_bt<1><<<(DH / 128) * (CAP / 128) * NE * nsplit, 256, 0, stream>>>(
      hbuf, W2t, b2, y0, DH, DI, DI / 64 / nsplit, DH / 128, CAP / 128, nsplit,
      (size_t)CAP * DI, (size_t)DH * DI, (size_t)CAP * DH, DH, (size_t)NTOK * DH);

  resid_ln<<<NTOK, 256, 0, stream>>>(y0, y1, nsplit - 1, x, gamma, beta, out);
}